// Round 3
// baseline (159.846 us; speedup 1.0000x reference)
//
#include <hip/hip_runtime.h>

// Upsample 2x (nearest) + horizontal 1x16 FIR (flattened 4x4 kernel), SAME pad.
// x: (32,512,512,1) fp32, kernel: 16 fp32, out: (32,1024,1024,1) fp32.
//
// Math (verified):
//  - conv is horizontal-only; upsampled rows 2r,2r+1 identical -> compute
//    once, store twice.
//  - up[p]=x[p>>1] collapses the 16-tap FIR to 9-tap (even) / 8-tap (odd)
//    polyphase filters on x; zero halo of 4 each side makes boundaries exact.
//
// R2 change: prefetch ALL 4 row-pairs into registers up front (64 B/lane in
// flight) so no iteration barriers on an outstanding HBM read; each block's
// read burst is fully separated from its write stream. Everything else
// (grid-stride 2048 blocks, 16B/lane nt loads/stores, double-buffered LDS,
// one barrier per pair) unchanged from the verified R1 kernel.

#define W_IN   512
#define H_IN   512
#define NB     32
#define W_OUT  1024
#define NPAIR  (NB * H_IN / 2)   // 8192 input row-pairs
#define NBLK   2048
#define ITERS  (NPAIR / NBLK)    // 4 pairs per block

typedef float f32x4 __attribute__((ext_vector_type(4)));

__global__ __launch_bounds__(256) void upsample_blur_kernel(
    const float* __restrict__ x,
    const float* __restrict__ kern,
    float* __restrict__ out)
{
    // rows[dbuf][rowInPair][520]; data at [4..515], zero halo [0..3],[516..519]
    __shared__ float rows[2][2][520];

    const int t = threadIdx.x;   // 0..255

    // ---- prefetch all ITERS row-pairs first: reads batched, latency hidden ----
    f32x4 xi[ITERS];
#pragma unroll
    for (int it = 0; it < ITERS; ++it) {
        const int pairIdx = blockIdx.x + it * NBLK;   // 0..NPAIR-1
        xi[it] = __builtin_nontemporal_load(
            reinterpret_cast<const f32x4*>(x + (size_t)pairIdx * (2 * W_IN)) + t);
    }

    // zero all four halo sets once (2 dbuf x 2 rows x 8 halo floats = 32)
    if (t < 32) {
        const int b  = t >> 4;          // dbuf
        const int rr = (t >> 3) & 1;    // row in pair
        const int i  = t & 7;
        rows[b][rr][(i < 4) ? i : (512 + i)] = 0.0f;
    }

    // flat 4x4 kernel (uniform -> scalar loads), collapsed polyphase taps
    float kf[16];
#pragma unroll
    for (int i = 0; i < 16; ++i) kf[i] = kern[i];

    float we[9], wo[8];
    we[0] = kf[0];
#pragma unroll
    for (int i = 0; i < 7; ++i) we[i + 1] = kf[2 * i + 1] + kf[2 * i + 2];
    we[8] = kf[15];
#pragma unroll
    for (int i = 0; i < 8; ++i) wo[i] = kf[2 * i] + kf[2 * i + 1];

    // staging map: thread t's 16B covers pair-local floats 4t..4t+3
    const int rsel = t >> 7;            // 0: first row of pair, 1: second
    const int csel = (4 * t) & 511;     // column within that row (multiple of 4)

    int buf = 0;
#pragma unroll
    for (int it = 0; it < ITERS; ++it) {
        const int pairIdx = blockIdx.x + it * NBLK;

        // ---- stage prefetched row-pair into LDS ----
        *reinterpret_cast<f32x4*>(&rows[buf][rsel][4 + csel]) = xi[it];

        __syncthreads();

        // ---- compute: thread t -> output cols 4t..4t+3 of both rows ----
        float v0[10], v1[10];
#pragma unroll
        for (int i = 0; i < 10; ++i) v0[i] = rows[buf][0][2 * t + i];
#pragma unroll
        for (int i = 0; i < 10; ++i) v1[i] = rows[buf][1][2 * t + i];

        float a0 = 0.f, a1 = 0.f, a2 = 0.f, a3 = 0.f;
        float b0 = 0.f, b1 = 0.f, b2 = 0.f, b3 = 0.f;
#pragma unroll
        for (int j = 0; j < 9; ++j) { a0 += we[j] * v0[j];     b0 += we[j] * v1[j];     }
#pragma unroll
        for (int j = 0; j < 8; ++j) { a1 += wo[j] * v0[j + 1]; b1 += wo[j] * v1[j + 1]; }
#pragma unroll
        for (int j = 0; j < 9; ++j) { a2 += we[j] * v0[j + 1]; b2 += we[j] * v1[j + 1]; }
#pragma unroll
        for (int j = 0; j < 8; ++j) { a3 += wo[j] * v0[j + 2]; b3 += wo[j] * v1[j + 2]; }

        f32x4 oa; oa.x = a0; oa.y = a1; oa.z = a2; oa.w = a3;
        f32x4 ob; ob.x = b0; ob.y = b1; ob.z = b2; ob.w = b3;

        // input row 2*pairIdx -> output rows 4*pairIdx .. 4*pairIdx+3 (contiguous)
        f32x4* o4 = reinterpret_cast<f32x4*>(out + (size_t)pairIdx * (4 * W_OUT));
        __builtin_nontemporal_store(oa, o4 + t);          // row 4p
        __builtin_nontemporal_store(oa, o4 + 256 + t);    // row 4p+1 (dup)
        __builtin_nontemporal_store(ob, o4 + 512 + t);    // row 4p+2
        __builtin_nontemporal_store(ob, o4 + 768 + t);    // row 4p+3 (dup)

        buf ^= 1;
        // no trailing barrier: next iter writes the OTHER LDS buffer; the
        // next iteration's barrier orders reuse of this one.
    }
}

extern "C" void kernel_launch(void* const* d_in, const int* in_sizes, int n_in,
                              void* d_out, int out_size, void* d_ws, size_t ws_size,
                              hipStream_t stream) {
    const float* x    = (const float*)d_in[0];
    const float* kern = (const float*)d_in[1];
    float* out        = (float*)d_out;

    upsample_blur_kernel<<<NBLK, 256, 0, stream>>>(x, kern, out);
}

// Round 4
// 158.238 us; speedup vs baseline: 1.0102x; 1.0102x over previous
//
#include <hip/hip_runtime.h>

// Upsample 2x (nearest) + horizontal 1x16 FIR (flattened 4x4 kernel), SAME pad.
// x: (32,512,512,1) fp32, kernel: 16 fp32, out: (32,1024,1024,1) fp32.
//
// Math (verified in prior rounds; this version is an exact re-indexing):
//  - conv is horizontal-only; upsampled rows 2r,2r+1 identical -> compute
//    once, store twice.
//  - up[p]=x[p>>1] collapses the 16-tap FIR to 9-tap (even cols, we[9]) /
//    8-tap (odd cols, wo[8]) polyphase filters on x; 4-wide zero halo each
//    side makes boundaries exact.
//  - even output w: sum_j we[j]*xz[w/2-4+j]; odd w: sum_j wo[j]*xz[(w-1)/2-3+j]
//
// R4 structure: NO LDS, NO barriers, NO loop — pure stream, shaped like the
// 6.4 TB/s fill kernel. Thread s computes output cols 8s..8s+7; its window
// xz[4s-4..4s+7] is exactly 3 aligned float4 chunks (neighbors overlap ->
// L1/L2 absorbs the 3x re-read; HBM fetch unchanged). Halo chunks are
// entirely zero (pad width 4 == chunk width) -> s==0 / s==127 select zero.
// Plain cached loads/stores (loads want caching now; stores rely on L2
// write-combining for the 16B-stride-32B lane pattern).

#define W_IN   512
#define H_IN   512
#define NB     32
#define W_OUT  1024
#define NPAIR  (NB * H_IN / 2)   // 8192 row-pairs, one block each

typedef float f32x4 __attribute__((ext_vector_type(4)));

__global__ __launch_bounds__(256) void upsample_blur_kernel(
    const float* __restrict__ x,
    const float* __restrict__ kern,
    float* __restrict__ out)
{
    const int t    = threadIdx.x;   // 0..255
    const int rsel = t >> 7;        // input row within the pair (0/1)
    const int s    = t & 127;       // col-group: output cols 8s..8s+7

    const int p      = blockIdx.x;        // row-pair index 0..NPAIR-1
    const int rowIn  = 2 * p + rsel;      // flat input row (n*512 + r)

    // ---- 3 aligned chunk loads: V[0..11] = xz[4s-4 .. 4s+7] ----
    const float* xr = x + (size_t)rowIn * W_IN;
    const f32x4 zero = {0.f, 0.f, 0.f, 0.f};
    const f32x4 cA = (s == 0)   ? zero : *reinterpret_cast<const f32x4*>(xr + 4 * s - 4);
    const f32x4 cB =                     *reinterpret_cast<const f32x4*>(xr + 4 * s);
    const f32x4 cC = (s == 127) ? zero : *reinterpret_cast<const f32x4*>(xr + 4 * s + 4);

    float V[12];
    V[0] = cA.x; V[1]  = cA.y; V[2]  = cA.z; V[3]  = cA.w;
    V[4] = cB.x; V[5]  = cB.y; V[6]  = cB.z; V[7]  = cB.w;
    V[8] = cC.x; V[9]  = cC.y; V[10] = cC.z; V[11] = cC.w;

    // ---- flat 4x4 kernel (uniform -> scalar loads), collapsed taps ----
    float kf[16];
#pragma unroll
    for (int i = 0; i < 16; ++i) kf[i] = kern[i];

    float we[9], wo[8];
    we[0] = kf[0];
#pragma unroll
    for (int i = 0; i < 7; ++i) we[i + 1] = kf[2 * i + 1] + kf[2 * i + 2];
    we[8] = kf[15];
#pragma unroll
    for (int i = 0; i < 8; ++i) wo[i] = kf[2 * i] + kf[2 * i + 1];

    // ---- 8 outputs: w = 8s + c ----
    // c even: o = sum_j we[j] * V[j + c/2]      (window xz[4s-4+c/2 + j])
    // c odd : o = sum_j wo[j] * V[j + (c+1)/2]
    float o[8];
#pragma unroll
    for (int c = 0; c < 8; c += 2) {
        float accE = 0.f, accO = 0.f;
        const int se = c / 2;        // shift for even output c
        const int so = c / 2 + 1;    // shift for odd output c+1
#pragma unroll
        for (int j = 0; j < 9; ++j) accE += we[j] * V[j + se];
#pragma unroll
        for (int j = 0; j < 8; ++j) accO += wo[j] * V[j + so];
        o[c]     = accE;
        o[c + 1] = accO;
    }

    f32x4 lo; lo.x = o[0]; lo.y = o[1]; lo.z = o[2]; lo.w = o[3];
    f32x4 hi; hi.x = o[4]; hi.y = o[5]; hi.z = o[6]; hi.w = o[7];

    // input row rowIn -> output rows 2*rowIn, 2*rowIn+1 (identical)
    const size_t ob = ((size_t)(4 * p + 2 * rsel)) * W_OUT + 8 * s;
    *reinterpret_cast<f32x4*>(out + ob)             = lo;
    *reinterpret_cast<f32x4*>(out + ob + 4)         = hi;
    *reinterpret_cast<f32x4*>(out + ob + W_OUT)     = lo;
    *reinterpret_cast<f32x4*>(out + ob + W_OUT + 4) = hi;
}

extern "C" void kernel_launch(void* const* d_in, const int* in_sizes, int n_in,
                              void* d_out, int out_size, void* d_ws, size_t ws_size,
                              hipStream_t stream) {
    const float* x    = (const float*)d_in[0];
    const float* kern = (const float*)d_in[1];
    float* out        = (float*)d_out;

    upsample_blur_kernel<<<NPAIR, 256, 0, stream>>>(x, kern, out);
}

// Round 5
// 155.073 us; speedup vs baseline: 1.0308x; 1.0204x over previous
//
#include <hip/hip_runtime.h>

// Upsample 2x (nearest) + horizontal 1x16 FIR (flattened 4x4 kernel), SAME pad.
// x: (32,512,512,1) fp32, kernel: 16 fp32, out: (32,1024,1024,1) fp32.
//
// R5 = exact revert to the prior session's best harness-verified kernel
// (154.2 us there). Four structurally disjoint variants (R2-R4: persistent
// grid / full read prefetch / pure-stream no-LDS-no-barrier) all measured
// 157.9-159.8 us; re-poison fills dominate the timed region and the kernel
// itself is <78 us (never in rocprof top-5). This submission is the A/B
// closing the loop: if it reproduces ~154-160, dur_us is at the harness
// floor and the session ends at the best-known kernel.
//
// Key reductions (verified):
//  - conv is horizontal-only and upsampled rows 2r,2r+1 are identical
//    -> output rows 2r,2r+1 identical: compute once, store twice.
//  - up[p]=x[p>>1] collapses the 16-tap FIR to 9-tap (even cols) / 8-tap
//    (odd cols) polyphase filters on x; with x zero-padded by 4 each side
//    the collapsed form is exact at boundaries.

#define W_IN  512
#define H_IN  512
#define NB    32
#define W_OUT 1024

__global__ __launch_bounds__(256) void upsample_blur_kernel(
    const float* __restrict__ x,
    const float* __restrict__ kern,
    float* __restrict__ out)
{
    // LDS row: indices 0..519; data at [4..515], zero halo [0..3] and [516..519]
    __shared__ float row[520];

    const int rowIdx = blockIdx.x;          // n*512 + r
    const int n = rowIdx >> 9;
    const int r = rowIdx & 511;
    const int t = threadIdx.x;              // 0..255

    // zero halos
    if (t < 8) {
        const int idx = (t < 4) ? t : (512 + t);   // 0..3, 516..519
        row[idx] = 0.0f;
    }

    // stage input row (512 floats) into LDS at offset 4 (16B-aligned -> float2 ok)
    const float* xrow = x + (size_t)(n * H_IN + r) * W_IN;
    reinterpret_cast<float2*>(row + 4)[t] = reinterpret_cast<const float2*>(xrow)[t];

    // load flat 4x4 kernel (uniform -> scalar-cached) and build collapsed taps
    float kf[16];
#pragma unroll
    for (int i = 0; i < 16; ++i) kf[i] = kern[i];

    float we[9], wo[8];
    we[0] = kf[0];
#pragma unroll
    for (int i = 0; i < 7; ++i) we[i + 1] = kf[2 * i + 1] + kf[2 * i + 2];
    we[8] = kf[15];
#pragma unroll
    for (int i = 0; i < 8; ++i) wo[i] = kf[2 * i] + kf[2 * i + 1];

    __syncthreads();

    // thread t computes output columns w = 4t..4t+3  (u = 2t, 2t+1)
    // needs xv[2t-4 .. 2t+5] = row[2t + 0 .. 2t + 9]
    float v[10];
#pragma unroll
    for (int i = 0; i < 10; ++i) v[i] = row[2 * t + i];   // stride-2: 2-way, free

    float o0 = 0.f, o1 = 0.f, o2 = 0.f, o3 = 0.f;
#pragma unroll
    for (int j = 0; j < 9; ++j) o0 += we[j] * v[j];       // w=4t   (even, u=2t)
#pragma unroll
    for (int j = 0; j < 8; ++j) o1 += wo[j] * v[j + 1];   // w=4t+1 (odd,  u=2t)
#pragma unroll
    for (int j = 0; j < 9; ++j) o2 += we[j] * v[j + 1];   // w=4t+2 (even, u=2t+1)
#pragma unroll
    for (int j = 0; j < 8; ++j) o3 += wo[j] * v[j + 2];   // w=4t+3 (odd,  u=2t+1)

    const float4 o = make_float4(o0, o1, o2, o3);
    const size_t outRowBase = ((size_t)n * W_OUT + 2 * r) * (size_t)W_OUT;
    float4* out4a = reinterpret_cast<float4*>(out + outRowBase);
    float4* out4b = reinterpret_cast<float4*>(out + outRowBase + W_OUT);
    out4a[t] = o;   // row 2r
    out4b[t] = o;   // row 2r+1 (identical)
}

extern "C" void kernel_launch(void* const* d_in, const int* in_sizes, int n_in,
                              void* d_out, int out_size, void* d_ws, size_t ws_size,
                              hipStream_t stream) {
    const float* x    = (const float*)d_in[0];
    const float* kern = (const float*)d_in[1];
    float* out        = (float*)d_out;

    const int numRows = NB * H_IN;   // 16384 blocks, one per input row
    upsample_blur_kernel<<<numRows, 256, 0, stream>>>(x, kern, out);
}